// Round 5
// baseline (351.353 us; speedup 1.0000x reference)
//
#include <hip/hip_runtime.h>
#include <stdint.h>

#define B 4
#define N 16384
#define D 512
#define H 256
#define NROWS (B * N)
#define K_SEL 11468
#define N_TOP 10322
#define N_RAND 1146
#define N_REM (N - N_TOP) /* 6062 */
#define HALF_CNT ((B * N_REM) / 2) /* 12124 */

typedef float f32x4 __attribute__((ext_vector_type(4)));
typedef _Float16 f16x8 __attribute__((ext_vector_type(8)));
typedef int i32x4 __attribute__((ext_vector_type(4)));

// async global->LDS 16B copy: LDS dest = wave-uniform base + lane*16
#define GLDS16(g, l)                                                    \
  __builtin_amdgcn_global_load_lds(                                     \
      (const __attribute__((address_space(1))) void*)(const void*)(g),  \
      (__attribute__((address_space(3))) void*)(void*)(l), 16, 0, 0)

// Monotone float -> uint key (larger float => larger key). No NaNs expected.
__device__ __forceinline__ uint32_t f2key(float x) {
  uint32_t u = __float_as_uint(x);
  return u ^ ((u & 0x80000000u) ? 0xFFFFFFFFu : 0x80000000u);
}

// ---- Threefry (matches jax.random.uniform(key(42)) stream) ---------------
__device__ __forceinline__ void threefry(uint32_t x0, uint32_t x1,
                                         uint32_t& o0, uint32_t& o1) {
  const uint32_t k0 = 0u, k1 = 42u;
  const uint32_t ks[3] = {k0, k1, k0 ^ k1 ^ 0x1BD11BDAu};
  x0 += ks[0];
  x1 += ks[1];
  const int R0[4] = {13, 15, 26, 6}, R1[4] = {17, 29, 16, 24};
#pragma unroll
  for (int i = 0; i < 5; ++i) {
    const int* R = (i & 1) ? R1 : R0;
#pragma unroll
    for (int jr = 0; jr < 4; ++jr) {
      x0 += x1;
      x1 = (x1 << R[jr]) | (x1 >> (32 - R[jr]));
      x1 ^= x0;
    }
    x0 += ks[(i + 1) % 3];
    x1 += ks[(i + 2) % 3] + (uint32_t)(i + 1);
  }
  o0 = x0;
  o1 = x1;
}

// ---- rand body: pick N_RAND smallest threefry scores -> psel bitmap ------
__device__ __forceinline__ void rand_body(const int b, int* __restrict__ psel,
                                          char* smem, const int t) {
  uint32_t* skey = reinterpret_cast<uint32_t*>(smem);           // N_REM*4
  uint32_t* hist = reinterpret_cast<uint32_t*>(smem + 24248);   // 256*4
  int* wr4 = reinterpret_cast<int*>(smem + 25272);              // 4*4
  uint32_t* shp = reinterpret_cast<uint32_t*>(smem + 25288);
  int* shrk = reinterpret_cast<int*>(smem + 25292);
  const int lane = t & 63, w4 = t >> 6;  // 4 waves

  for (int p = t; p < N_REM; p += 256) {
    psel[b * N_REM + p] = 0;
    const int f = b * N_REM + p;
    uint32_t o0, o1, bits;
    if (f < HALF_CNT) {
      threefry((uint32_t)f, (uint32_t)(f + HALF_CNT), o0, o1);
      bits = o0;
    } else {
      threefry((uint32_t)(f - HALF_CNT), (uint32_t)f, o0, o1);
      bits = o1;
    }
    const float u = __uint_as_float((bits >> 9) | 0x3f800000u) - 1.0f;
    skey[p] = f2key(u);
  }
  __syncthreads();

  uint32_t prefix = 0;
  int rk = N_RAND;
  for (int pass = 3; pass >= 0; --pass) {
    const int sh = pass * 8;
    hist[t] = 0;
    __syncthreads();
    for (int p = t; p < N_REM; p += 256) {
      const uint32_t key = skey[p];
      if (pass == 3 || (key >> (sh + 8)) == (prefix >> (sh + 8)))
        atomicAdd(&hist[(key >> sh) & 255], 1u);
    }
    __syncthreads();
    const int h = (int)hist[t];
    int v = h;
#pragma unroll
    for (int off = 1; off < 64; off <<= 1) {
      const int u2 = __shfl_up(v, off, 64);
      if (lane >= off) v += u2;
    }
    if (lane == 63) wr4[w4] = v;
    __syncthreads();
    int add = 0;
    for (int i = 0; i < w4; ++i) add += wr4[i];
    const int incl = v + add, excl = incl - h;
    if (incl >= rk && excl < rk) {
      *shp = prefix | ((uint32_t)t << sh);
      *shrk = rk - excl;
    }
    __syncthreads();
    prefix = *shp;
    rk = *shrk;
    __syncthreads();
  }

  const int CH = 24;  // 256*24 >= 6062
  const int p0 = t * CH;
  const int pe = (p0 + CH < N_REM) ? p0 + CH : N_REM;
  int ce = 0;
  for (int p = p0; p < pe; ++p) ce += (skey[p] == prefix);
  int v = ce;
#pragma unroll
  for (int off = 1; off < 64; off <<= 1) {
    const int u2 = __shfl_up(v, off, 64);
    if (lane >= off) v += u2;
  }
  if (lane == 63) wr4[w4] = v;
  __syncthreads();
  if (t == 0) {
    int run = 0;
    for (int i = 0; i < 4; ++i) {
      const int a = wr4[i];
      wr4[i] = run;
      run += a;
    }
  }
  __syncthreads();
  int ge = wr4[w4] + v - ce;
  for (int p = p0; p < pe; ++p) {
    const uint32_t key = skey[p];
    const bool pick = (key < prefix) || (key == prefix && ge < rk);
    ge += (key == prefix);
    if (pick) psel[b * N_REM + p] = 1;
  }
}

// ---- K0: fused prep. Blocks 0-63: W^T fp16 hi/lo, step-chunked AND
// granule-permuted: within row n (64 B = 4 granules of 16 B), source granule
// g lands at slot g ^ ((n>>1)&3). score's swizzled frag reads then see
// 8 distinct bank-quads per quarter-wave (2-way = free) instead of 8-way
// conflicts, while global_load_lds keeps a linear dest (rule #21).
// Blocks 64-67: rand selection (independent, overlapped).
__global__ __launch_bounds__(256) void prep_kernel(
    const float* __restrict__ WV, const float* __restrict__ WU,
    _Float16* __restrict__ wt_h, _Float16* __restrict__ wt_l,
    int* __restrict__ psel) {
  __shared__ __align__(16) char pmem[25296];
  if (blockIdx.x >= 64) {
    rand_body(blockIdx.x - 64, psel, pmem, threadIdx.x);
    return;
  }
  _Float16(*th)[65] = reinterpret_cast<_Float16(*)[65]>(pmem);
  _Float16(*tl)[65] = reinterpret_cast<_Float16(*)[65]>(pmem + 8320);
  const int kb = (blockIdx.x >> 3) * 64;
  const int nb = (blockIdx.x & 7) * 64;
  const int tx = threadIdx.x & 63;
  const int ty = threadIdx.x >> 6;
  const float* src = (nb < 256) ? WV : WU;
  const int nsrc = nb & 255;
#pragma unroll
  for (int i = 0; i < 16; ++i) {
    const int k = ty + i * 4;
    const float x = src[(size_t)(kb + k) * H + nsrc + tx];
    const _Float16 h = (_Float16)x;
    th[k][tx] = h;
    tl[k][tx] = (_Float16)(x - (float)h);
  }
  __syncthreads();
  const int n_local = threadIdx.x & 63;
  const int c2 = threadIdx.x >> 6;
  const int s_local = c2 >> 1, half = c2 & 1;
  const int n = nb + n_local;
  const int s = (kb >> 5) + s_local;
  const int klb = s_local * 32 + half * 16;
  const int swz = (n_local >> 1) & 3;  // (n>>1)&3, nb%64==0
  f16x8 vh0, vh1, vl0, vl1;
#pragma unroll
  for (int e = 0; e < 8; ++e) {
    vh0[e] = th[klb + e][n_local];
    vh1[e] = th[klb + 8 + e][n_local];
    vl0[e] = tl[klb + e][n_local];
    vl1[e] = tl[klb + 8 + e][n_local];
  }
  const size_t orow = (size_t)s * 16384 + (size_t)n * 32;
  *reinterpret_cast<f16x8*>(wt_h + orow + (((2 * half) ^ swz) * 8)) = vh0;
  *reinterpret_cast<f16x8*>(wt_h + orow + (((2 * half + 1) ^ swz) * 8)) = vh1;
  *reinterpret_cast<f16x8*>(wt_l + orow + (((2 * half) ^ swz) * 8)) = vl0;
  *reinterpret_cast<f16x8*>(wt_l + orow + (((2 * half + 1) ^ swz) * 8)) = vl1;
}

// ---- K1: fused gated-attention raw scores via MFMA (fp16 hi/lo split).
// 512 wg x 512 thr. BM=128, BN=512, K-step 32, 16 steps.
// R5: + XOR granule swizzle on A/B (bank-conflict-free frag reads),
//     + A-convert hoisted into MFMA shadow (bar1->bar2 = 2 ds_writes only),
//     + setprio around MFMA cluster, + one-ahead B-frag prefetch.
// Math/order bit-identical to R2-R4.
__global__ __launch_bounds__(512) void score_kernel(
    const float* __restrict__ feat, const _Float16* __restrict__ wt_h,
    const _Float16* __restrict__ wt_l, const float* __restrict__ bV,
    const float* __restrict__ bU, const float* __restrict__ watt,
    float* __restrict__ raw) {
  __shared__ _Float16 Ah[128 * 32];    // 8 KB
  __shared__ _Float16 Al[128 * 32];    // 8 KB
  __shared__ _Float16 Bh0[512 * 32];   // 32 KB
  __shared__ _Float16 Bl0[512 * 32];   // 32 KB
  __shared__ _Float16 Bh1[512 * 32];   // 32 KB
  __shared__ _Float16 Bl1[512 * 32];   // 32 KB
  __shared__ float red[128][5];        // 2.5 KB

  const int tid = threadIdx.x;
  const int lane = tid & 63;
  const int lc = lane & 15;
  const int lg = lane >> 4;
  const int w = __builtin_amdgcn_readfirstlane(tid >> 6);
  const int rg = w >> 2;  // 0..1
  const int cg = w & 3;   // 0..3
  const int row0 = blockIdx.x * 128;

  // A staging: thread covers row rA, granule gA (8 floats); swizzled write
  const int rA = tid >> 2;
  const int gA = tid & 3;
  const float* aG = feat + (size_t)(row0 + rA) * D + gA * 8;
  const int awOff = rA * 32 + ((gA ^ ((rA >> 1) & 3)) << 3);

  // B staging via global_load_lds: wave w covers f16 range [w*2048, +2048)
  const _Float16* pbh = wt_h + (size_t)w * 2048 + lane * 8;
  const _Float16* pbl = wt_l + (size_t)w * 2048 + lane * 8;
  const int ldsB = w * 2048;  // f16 idx

  // frag read offsets (step-invariant, f16 elems). For both A and B rows,
  // (row>>1)&3 == (lc>>1)&3 since the row base is a multiple of 16.
  const int rswz = (lc >> 1) & 3;
  int aoff[4], boff[8];
#pragma unroll
  for (int mt = 0; mt < 4; ++mt)
    aoff[mt] = (rg * 64 + mt * 16 + lc) * 32 + ((lg ^ rswz) << 3);
#pragma unroll
  for (int nt = 0; nt < 8; ++nt) {
    const int nbase =
        (nt < 4) ? cg * 64 + nt * 16 : 256 + cg * 64 + (nt - 4) * 16;
    boff[nt] = (nbase + lc) * 32 + ((lg ^ rswz) << 3);
  }

  f32x4 acc[4][8] = {};
  f32x4 a0, a1;

  // ---- prologue: stage step 0 ----
  a0 = *(const f32x4*)(aG);
  a1 = *(const f32x4*)(aG + 4);
#pragma unroll
  for (int i = 0; i < 4; ++i) {
    GLDS16(pbh + i * 512, &Bh0[ldsB + i * 512]);
    GLDS16(pbl + i * 512, &Bl0[ldsB + i * 512]);
  }
  {
    f16x8 ahw, alw;
#pragma unroll
    for (int e = 0; e < 8; ++e) {
      const float x = (e < 4) ? a0[e] : a1[e - 4];
      const _Float16 h = (_Float16)x;
      ahw[e] = h;
      alw[e] = (_Float16)(x - (float)h);
    }
    *(f16x8*)&Ah[awOff] = ahw;
    *(f16x8*)&Al[awOff] = alw;
  }
  __syncthreads();

#pragma unroll 1
  for (int kt = 0; kt < 16; ++kt) {
    const int knx = (kt + 1) & 15;  // wrap: last iter restages step 0 (unused)
    _Float16* BhN = (kt & 1) ? Bh0 : Bh1;
    _Float16* BlN = (kt & 1) ? Bl0 : Bl1;
    const _Float16* BhC = (kt & 1) ? Bh1 : Bh0;
    const _Float16* BlC = (kt & 1) ? Bl1 : Bl0;

    // issue next-step B (async -> LDS buf^1) and A (-> regs) EARLY
#pragma unroll
    for (int i = 0; i < 4; ++i) {
      GLDS16(pbh + knx * 16384 + i * 512, &BhN[ldsB + i * 512]);
      GLDS16(pbl + knx * 16384 + i * 512, &BlN[ldsB + i * 512]);
    }
    a0 = *(const f32x4*)(aG + knx * 32);
    a1 = *(const f32x4*)(aG + knx * 32 + 4);
    __builtin_amdgcn_sched_barrier(0);  // pin load issue before compute

    // ---- compute step kt ----
    f16x8 ah[4], al[4];
#pragma unroll
    for (int mt = 0; mt < 4; ++mt) {
      ah[mt] = *(const f16x8*)&Ah[aoff[mt]];
      al[mt] = *(const f16x8*)&Al[aoff[mt]];
    }
    f16x8 bh = *(const f16x8*)&BhC[boff[0]];
    f16x8 bl = *(const f16x8*)&BlC[boff[0]];
    __builtin_amdgcn_s_setprio(1);
#pragma unroll
    for (int nt = 0; nt < 8; ++nt) {
      f16x8 bhn, bln;
      if (nt < 7) {
        bhn = *(const f16x8*)&BhC[boff[nt + 1]];
        bln = *(const f16x8*)&BlC[boff[nt + 1]];
      }
#pragma unroll
      for (int mt = 0; mt < 4; ++mt) {
        acc[mt][nt] = __builtin_amdgcn_mfma_f32_16x16x32_f16(ah[mt], bh,
                                                             acc[mt][nt], 0, 0, 0);
        acc[mt][nt] = __builtin_amdgcn_mfma_f32_16x16x32_f16(ah[mt], bl,
                                                             acc[mt][nt], 0, 0, 0);
        acc[mt][nt] = __builtin_amdgcn_mfma_f32_16x16x32_f16(al[mt], bh,
                                                             acc[mt][nt], 0, 0, 0);
      }
      bh = bhn;
      bl = bln;
    }
    __builtin_amdgcn_s_setprio(0);

    // convert A(knx) in the MFMA shadow (VALU; depends only on a0/a1)
    f16x8 ahw, alw;
#pragma unroll
    for (int e = 0; e < 8; ++e) {
      const float x = (e < 4) ? a0[e] : a1[e - 4];
      const _Float16 h = (_Float16)x;
      ahw[e] = h;
      alw[e] = (_Float16)(x - (float)h);
    }
    __syncthreads();  // bar1: A-tile reads done; drains B(knx)
    *(f16x8*)&Ah[awOff] = ahw;
    *(f16x8*)&Al[awOff] = alw;
    __syncthreads();  // bar2: A(knx) visible
  }

  // ---- epilogue: gate + reduce over this wave's 64 j-columns ----
#pragma unroll
  for (int mt = 0; mt < 4; ++mt) {
    float rs[4] = {0.f, 0.f, 0.f, 0.f};
#pragma unroll
    for (int nt = 0; nt < 4; ++nt) {
      const int j = cg * 64 + nt * 16 + lc;
      const float bv = bV[j], bu = bU[j], wa = watt[j];
#pragma unroll
      for (int rr = 0; rr < 4; ++rr) {
        const float cV = acc[mt][nt][rr] + bv;
        const float cU = acc[mt][nt + 4][rr] + bu;
        const float e2 = __expf(2.0f * cV);
        const float aV = 1.0f - 2.0f / (e2 + 1.0f);    // tanh
        const float aU = 1.0f / (1.0f + __expf(-cU));  // sigmoid
        rs[rr] += aV * aU * wa;
      }
    }
#pragma unroll
    for (int rr = 0; rr < 4; ++rr) {
      float v = rs[rr];
      v += __shfl_xor(v, 1, 16);
      v += __shfl_xor(v, 2, 16);
      v += __shfl_xor(v, 4, 16);
      v += __shfl_xor(v, 8, 16);
      if (lc == 0) red[rg * 64 + mt * 16 + lg * 4 + rr][cg] = v;
    }
  }
  __syncthreads();
  if (tid < 128)
    raw[row0 + tid] = red[tid][0] + red[tid][1] + red[tid][2] + red[tid][3];
}

// ---- exclusive scan over 1024 per-thread counts --------------------------
__device__ __forceinline__ int scan1024(int c, int* wred, int tid) {
  const int lane = tid & 63, w = tid >> 6;
  int v = c;
#pragma unroll
  for (int off = 1; off < 64; off <<= 1) {
    const int u = __shfl_up(v, off, 64);
    if (lane >= off) v += u;
  }
  if (lane == 63) wred[w] = v;
  __syncthreads();
  if (tid == 0) {
    int run = 0;
    for (int i = 0; i < 16; ++i) {
      const int a = wred[i];
      wred[i] = run;
      run += a;
    }
  }
  __syncthreads();
  const int res = wred[w] + v - c;
  __syncthreads();
  return res;
}

// ---- K3: fused softmax + top-k threshold + membership + compaction -------
__global__ __launch_bounds__(1024) void select_kernel(
    const float* __restrict__ raw, const int* __restrict__ psel,
    float* __restrict__ attn_out, int* __restrict__ sel_ws,
    float* __restrict__ out_selidx) {
  const int b = blockIdx.x, t = threadIdx.x;
  const int lane = t & 63, w = t >> 6;
  __shared__ float sraw[N];        // 64 KB
  __shared__ int whist[16][256];   // 16 KB
  __shared__ int ghist[256];
  __shared__ float fred[16];
  __shared__ int wred[16];
  __shared__ float shM, shS;
  __shared__ uint32_t sh_prefix;
  __shared__ int sh_rk;
  const float* r = raw + b * N;

  // 1. load + max
  float m = -3.0e38f;
  for (int i = 0; i < 16; ++i) {
    const int idx = t + i * 1024;
    const float v = r[idx];
    sraw[idx] = v;
    m = fmaxf(m, v);
  }
  for (int off = 32; off > 0; off >>= 1) m = fmaxf(m, __shfl_down(m, off, 64));
  if (lane == 0) fred[w] = m;
  __syncthreads();
  if (t == 0) {
    float mm = fred[0];
    for (int i = 1; i < 16; ++i) mm = fmaxf(mm, fred[i]);
    shM = mm;
  }
  __syncthreads();
  const float M = shM;

  // 2. sum exp (keep the 16 exps in registers for step 3)
  float ex[16];
  float s = 0.f;
  for (int i = 0; i < 16; ++i) {
    ex[i] = expf(sraw[t + i * 1024] - M);
    s += ex[i];
  }
  for (int off = 32; off > 0; off >>= 1) s += __shfl_down(s, off, 64);
  if (lane == 0) fred[w] = s;
  __syncthreads();
  if (t == 0) {
    float ss = 0.f;
    for (int i = 0; i < 16; ++i) ss += fred[i];
    shS = ss;
  }
  __syncthreads();
  const float inv = 1.0f / shS;

  // 3. attn write
  for (int i = 0; i < 16; ++i)
    attn_out[b * N + t + i * 1024] = ex[i] * inv;

  // 4. radix select: threshold key + stable tie count
  uint32_t prefix = 0;
  int rk = N_TOP;
  for (int pass = 3; pass >= 0; --pass) {
    const int sh = pass * 8;
#pragma unroll
    for (int q = 0; q < 4; ++q) whist[w][lane * 4 + q] = 0;
    __syncthreads();
    for (int i = 0; i < 16; ++i) {
      const uint32_t key = f2key(sraw[t + i * 1024]);
      if (pass == 3 || (key >> (sh + 8)) == (prefix >> (sh + 8)))
        atomicAdd(&whist[w][(key >> sh) & 255], 1);
    }
    __syncthreads();
    if (t < 256) {
      int tot = 0;
      for (int ww = 0; ww < 16; ++ww) tot += whist[ww][t];
      ghist[t] = tot;
    }
    __syncthreads();
    int vS = 0, hrev = 0;
    if (t < 256) {
      hrev = ghist[255 - t];
      vS = hrev;
#pragma unroll
      for (int off = 1; off < 64; off <<= 1) {
        const int u2 = __shfl_up(vS, off, 64);
        if (lane >= off) vS += u2;
      }
      if (lane == 63) wred[t >> 6] = vS;
    }
    __syncthreads();
    if (t < 256) {
      int add = 0;
      const int w4 = t >> 6;
      for (int i = 0; i < w4; ++i) add += wred[i];
      const int incl = vS + add, excl = incl - hrev;
      if (incl >= rk && excl < rk) {
        sh_prefix = prefix | ((uint32_t)(255 - t) << sh);
        sh_rk = rk - excl;
      }
    }
    __syncthreads();
    prefix = sh_prefix;
    rk = sh_rk;
    __syncthreads();
  }
  const uint32_t T = prefix;
  const int tieTake = rk;

  // 5. membership + p-rank + psel lookup + selection (contiguous chunks)
  const int n0 = t * 16;
  int cgt = 0, ceq = 0;
  for (int i = 0; i < 16; ++i) {
    const uint32_t key = f2key(sraw[n0 + i]);
    cgt += (key > T);
    ceq += (key == T);
  }
  const int gbase = scan1024(cgt, wred, t);
  const int ebase = scan1024(ceq, wred, t);
  int grun = gbase, erun = ebase;
  unsigned selmask = 0;
  int csel = 0;
  for (int i = 0; i < 16; ++i) {
    const int n = n0 + i;
    const uint32_t key = f2key(sraw[n]);
    const bool gt = key > T, eq = key == T;
    const bool mem = gt || (eq && erun < tieTake);
    int sel;
    if (mem) {
      sel = 1;
    } else {
      const int members_before = grun + (erun < tieTake ? erun : tieTake);
      const int p = n - members_before;
      sel = psel[b * N_REM + p];
    }
    selmask |= (unsigned)sel << i;
    csel += sel;
    grun += gt;
    erun += eq;
  }
  int q = scan1024(csel, wred, t);
  for (int i = 0; i < 16; ++i) {
    if ((selmask >> i) & 1) {
      const int n = n0 + i;
      sel_ws[b * K_SEL + q] = n;
      out_selidx[b * K_SEL + q] = (float)n;
      ++q;
    }
  }
}

// ---- K4: gather selected feature rows ------------------------------------
__global__ __launch_bounds__(128) void gather_kernel(
    const float* __restrict__ feat, const int* __restrict__ sel_ws,
    float* __restrict__ out_sel) {
  const int qa = blockIdx.x;
  const int b = qa / K_SEL;
  const int n = sel_ws[qa];
  const float4* src =
      reinterpret_cast<const float4*>(feat + (size_t)(b * N + n) * D);
  float4* dst = reinterpret_cast<float4*>(out_sel + (size_t)qa * D);
  dst[threadIdx.x] = src[threadIdx.x];
}

extern "C" void kernel_launch(void* const* d_in, const int* in_sizes, int n_in,
                              void* d_out, int out_size, void* d_ws,
                              size_t ws_size, hipStream_t stream) {
  const float* feat = (const float*)d_in[0];
  const float* WV = (const float*)d_in[1];
  const float* bV = (const float*)d_in[2];
  const float* WU = (const float*)d_in[3];
  const float* bU = (const float*)d_in[4];
  const float* watt = (const float*)d_in[5];
  const float* batt = (const float*)d_in[6];
  (void)batt;  // softmax is shift-invariant; b_att cancels in all outputs

  float* out = (float*)d_out;
  float* out_selected = out;                      // B*K_SEL*D floats
  float* out_attn = out + (size_t)B * K_SEL * D;  // B*N floats
  float* out_selidx = out_attn + (size_t)B * N;   // B*K_SEL floats

  _Float16* wt_h = (_Float16*)d_ws;            // 512*512 fp16 = 512 KB
  _Float16* wt_l = wt_h + 512 * 512;           // 512 KB
  float* raw = (float*)(wt_l + 512 * 512);     // NROWS floats
  int* psel = (int*)(raw + NROWS);             // B*N_REM
  int* sel_ws = psel + B * N_REM;              // B*K_SEL

  prep_kernel<<<68, 256, 0, stream>>>(WV, WU, wt_h, wt_l, psel);
  score_kernel<<<NROWS / 128, 512, 0, stream>>>(feat, wt_h, wt_l, bV, bU, watt,
                                                raw);
  select_kernel<<<B, 1024, 0, stream>>>(raw, psel, out_attn, sel_ws,
                                        out_selidx);
  gather_kernel<<<B * K_SEL, 128, 0, stream>>>(feat, sel_ws, out_selected);
}

// Round 7
// 342.478 us; speedup vs baseline: 1.0259x; 1.0259x over previous
//
#include <hip/hip_runtime.h>
#include <stdint.h>

#define B 4
#define N 16384
#define D 512
#define H 256
#define NROWS (B * N)
#define K_SEL 11468
#define N_TOP 10322
#define N_RAND 1146
#define N_REM (N - N_TOP) /* 6062 */
#define HALF_CNT ((B * N_REM) / 2) /* 12124 */

typedef float f32x4 __attribute__((ext_vector_type(4)));
typedef _Float16 f16x8 __attribute__((ext_vector_type(8)));
typedef int i32x4 __attribute__((ext_vector_type(4)));

// async global->LDS 16B copy: LDS dest = wave-uniform base + lane*16
#define GLDS16(g, l)                                                    \
  __builtin_amdgcn_global_load_lds(                                     \
      (const __attribute__((address_space(1))) void*)(const void*)(g),  \
      (__attribute__((address_space(3))) void*)(void*)(l), 16, 0, 0)

// Monotone float -> uint key (larger float => larger key). No NaNs expected.
__device__ __forceinline__ uint32_t f2key(float x) {
  uint32_t u = __float_as_uint(x);
  return u ^ ((u & 0x80000000u) ? 0xFFFFFFFFu : 0x80000000u);
}

// ---- Threefry (matches jax.random.uniform(key(42)) stream) ---------------
__device__ __forceinline__ void threefry(uint32_t x0, uint32_t x1,
                                         uint32_t& o0, uint32_t& o1) {
  const uint32_t k0 = 0u, k1 = 42u;
  const uint32_t ks[3] = {k0, k1, k0 ^ k1 ^ 0x1BD11BDAu};
  x0 += ks[0];
  x1 += ks[1];
  const int R0[4] = {13, 15, 26, 6}, R1[4] = {17, 29, 16, 24};
#pragma unroll
  for (int i = 0; i < 5; ++i) {
    const int* R = (i & 1) ? R1 : R0;
#pragma unroll
    for (int jr = 0; jr < 4; ++jr) {
      x0 += x1;
      x1 = (x1 << R[jr]) | (x1 >> (32 - R[jr]));
      x1 ^= x0;
    }
    x0 += ks[(i + 1) % 3];
    x1 += ks[(i + 2) % 3] + (uint32_t)(i + 1);
  }
  o0 = x0;
  o1 = x1;
}

// ---- rand body: pick N_RAND smallest threefry scores -> psel bitmap ------
__device__ __forceinline__ void rand_body(const int b, int* __restrict__ psel,
                                          char* smem, const int t) {
  uint32_t* skey = reinterpret_cast<uint32_t*>(smem);           // N_REM*4
  uint32_t* hist = reinterpret_cast<uint32_t*>(smem + 24248);   // 256*4
  int* wr4 = reinterpret_cast<int*>(smem + 25272);              // 4*4
  uint32_t* shp = reinterpret_cast<uint32_t*>(smem + 25288);
  int* shrk = reinterpret_cast<int*>(smem + 25292);
  const int lane = t & 63, w4 = t >> 6;  // 4 waves

  for (int p = t; p < N_REM; p += 256) {
    psel[b * N_REM + p] = 0;
    const int f = b * N_REM + p;
    uint32_t o0, o1, bits;
    if (f < HALF_CNT) {
      threefry((uint32_t)f, (uint32_t)(f + HALF_CNT), o0, o1);
      bits = o0;
    } else {
      threefry((uint32_t)(f - HALF_CNT), (uint32_t)f, o0, o1);
      bits = o1;
    }
    const float u = __uint_as_float((bits >> 9) | 0x3f800000u) - 1.0f;
    skey[p] = f2key(u);
  }
  __syncthreads();

  uint32_t prefix = 0;
  int rk = N_RAND;
  for (int pass = 3; pass >= 0; --pass) {
    const int sh = pass * 8;
    hist[t] = 0;
    __syncthreads();
    for (int p = t; p < N_REM; p += 256) {
      const uint32_t key = skey[p];
      if (pass == 3 || (key >> (sh + 8)) == (prefix >> (sh + 8)))
        atomicAdd(&hist[(key >> sh) & 255], 1u);
    }
    __syncthreads();
    const int h = (int)hist[t];
    int v = h;
#pragma unroll
    for (int off = 1; off < 64; off <<= 1) {
      const int u2 = __shfl_up(v, off, 64);
      if (lane >= off) v += u2;
    }
    if (lane == 63) wr4[w4] = v;
    __syncthreads();
    int add = 0;
    for (int i = 0; i < w4; ++i) add += wr4[i];
    const int incl = v + add, excl = incl - h;
    if (incl >= rk && excl < rk) {
      *shp = prefix | ((uint32_t)t << sh);
      *shrk = rk - excl;
    }
    __syncthreads();
    prefix = *shp;
    rk = *shrk;
    __syncthreads();
  }

  const int CH = 24;  // 256*24 >= 6062
  const int p0 = t * CH;
  const int pe = (p0 + CH < N_REM) ? p0 + CH : N_REM;
  int ce = 0;
  for (int p = p0; p < pe; ++p) ce += (skey[p] == prefix);
  int v = ce;
#pragma unroll
  for (int off = 1; off < 64; off <<= 1) {
    const int u2 = __shfl_up(v, off, 64);
    if (lane >= off) v += u2;
  }
  if (lane == 63) wr4[w4] = v;
  __syncthreads();
  if (t == 0) {
    int run = 0;
    for (int i = 0; i < 4; ++i) {
      const int a = wr4[i];
      wr4[i] = run;
      run += a;
    }
  }
  __syncthreads();
  int ge = wr4[w4] + v - ce;
  for (int p = p0; p < pe; ++p) {
    const uint32_t key = skey[p];
    const bool pick = (key < prefix) || (key == prefix && ge < rk);
    ge += (key == prefix);
    if (pick) psel[b * N_REM + p] = 1;
  }
}

// ---- K0: fused prep. Blocks 0-63: W^T fp16 hi/lo, step- AND col-half-
// chunked + granule-permuted:
//   elem(s, c, nl, k16slot): off = s*16384 + c*8192 + nl*32 + slot*8
//   where for V col j: c=j>>7, nl=j&127; for U col j: c=j>>7, nl=128+(j&127);
//   slot = g ^ ((nl>>1)&3)  (g = k16-granule; bank-conflict-free frag reads
//   in score while global_load_lds keeps a linear dest, rule #21).
// Blocks 64-67: rand selection (independent, overlapped).
__global__ __launch_bounds__(256) void prep_kernel(
    const float* __restrict__ WV, const float* __restrict__ WU,
    _Float16* __restrict__ wt_h, _Float16* __restrict__ wt_l,
    int* __restrict__ psel) {
  __shared__ __align__(16) char pmem[25296];
  if (blockIdx.x >= 64) {
    rand_body(blockIdx.x - 64, psel, pmem, threadIdx.x);
    return;
  }
  _Float16(*th)[65] = reinterpret_cast<_Float16(*)[65]>(pmem);
  _Float16(*tl)[65] = reinterpret_cast<_Float16(*)[65]>(pmem + 8320);
  const int kb = (blockIdx.x >> 3) * 64;
  const int nb = (blockIdx.x & 7) * 64;
  const int tx = threadIdx.x & 63;
  const int ty = threadIdx.x >> 6;
  const float* src = (nb < 256) ? WV : WU;
  const int nsrc = nb & 255;
#pragma unroll
  for (int i = 0; i < 16; ++i) {
    const int k = ty + i * 4;
    const float x = src[(size_t)(kb + k) * H + nsrc + tx];
    const _Float16 h = (_Float16)x;
    th[k][tx] = h;
    tl[k][tx] = (_Float16)(x - (float)h);
  }
  __syncthreads();
  const int n_local = threadIdx.x & 63;
  const int c2 = threadIdx.x >> 6;
  const int s_local = c2 >> 1, half = c2 & 1;
  const int n = nb + n_local;  // global n (0..255 V, 256..511 U)
  const int s = (kb >> 5) + s_local;
  const int klb = s_local * 32 + half * 16;
  // col-half chunk coordinates
  const int j = (n < 256) ? n : n - 256;
  const int ch = j >> 7;
  const int nl = ((n < 256) ? 0 : 128) + (j & 127);
  const int swz = (nl >> 1) & 3;  // == (n>>1)&3
  f16x8 vh0, vh1, vl0, vl1;
#pragma unroll
  for (int e = 0; e < 8; ++e) {
    vh0[e] = th[klb + e][n_local];
    vh1[e] = th[klb + 8 + e][n_local];
    vl0[e] = tl[klb + e][n_local];
    vl1[e] = tl[klb + 8 + e][n_local];
  }
  const size_t orow = (size_t)s * 16384 + (size_t)ch * 8192 + (size_t)nl * 32;
  *reinterpret_cast<f16x8*>(wt_h + orow + (((2 * half) ^ swz) * 8)) = vh0;
  *reinterpret_cast<f16x8*>(wt_h + orow + (((2 * half + 1) ^ swz) * 8)) = vh1;
  *reinterpret_cast<f16x8*>(wt_l + orow + (((2 * half) ^ swz) * 8)) = vl0;
  *reinterpret_cast<f16x8*>(wt_l + orow + (((2 * half + 1) ^ swz) * 8)) = vl1;
}

// ---- K1: fused gated-attention raw scores via MFMA (fp16 hi/lo split).
// R6: col-split. 1024 wg x 512 thr; block = (rowtile = bid>>1, c = bid&1).
// BM=128 rows x BN=256 cols (128 V j's + paired 128 U j's), K-step 32.
// acc[4][4] (64 regs) + LDS exactly 80 KB (B dbuf 64K + A 16K, red aliases
// Ah) + __launch_bounds__(512,4) => 2 blocks/CU, 4 waves/SIMD: the other
// block's MFMAs hide this block's barriers/staging.
// Each block writes a partial row sum; select adds the two partials
// (2-term sum is order-independent; no atomics).
__global__ __launch_bounds__(512, 4) void score_kernel(
    const float* __restrict__ feat, const _Float16* __restrict__ wt_h,
    const _Float16* __restrict__ wt_l, const float* __restrict__ bV,
    const float* __restrict__ bU, const float* __restrict__ watt,
    float* __restrict__ rawp) {
  __shared__ _Float16 Ah[128 * 32];   // 8 KB
  __shared__ _Float16 Al[128 * 32];   // 8 KB
  __shared__ _Float16 Bh0[256 * 32];  // 16 KB
  __shared__ _Float16 Bl0[256 * 32];  // 16 KB
  __shared__ _Float16 Bh1[256 * 32];  // 16 KB
  __shared__ _Float16 Bl1[256 * 32];  // 16 KB
  float* red = reinterpret_cast<float*>(Ah);  // [128][5] epilogue alias

  const int tid = threadIdx.x;
  const int lane = tid & 63;
  const int lc = lane & 15;
  const int lg = lane >> 4;
  const int w = __builtin_amdgcn_readfirstlane(tid >> 6);
  const int rg = w >> 2;  // 0..1
  const int cg = w & 3;   // 0..3
  const int bid = blockIdx.x;
  const int c = bid & 1;
  const int row0 = (bid >> 1) * 128;

  // A staging: thread covers row rA, granule gA (8 floats); swizzled write
  const int rA = tid >> 2;
  const int gA = tid & 3;
  const float* aG = feat + (size_t)(row0 + rA) * D + gA * 8;
  const int awOff = rA * 32 + ((gA ^ ((rA >> 1) & 3)) << 3);

  // B staging via global_load_lds: per step chunk = 8192 f16 at
  // s*16384 + c*8192; wave w covers [w*1024, +1024) in 2 issues of 512.
  const _Float16* pbh = wt_h + (size_t)c * 8192 + (size_t)w * 1024 + lane * 8;
  const _Float16* pbl = wt_l + (size_t)c * 8192 + (size_t)w * 1024 + lane * 8;
  const int ldsB = w * 1024;  // f16 idx

  // frag read offsets (step-invariant, f16 elems); row bases are x16 so
  // (row>>1)&3 == (lc>>1)&3.
  const int rswz = (lc >> 1) & 3;
  int aoff[4], boff[4];
#pragma unroll
  for (int mt = 0; mt < 4; ++mt)
    aoff[mt] = (rg * 64 + mt * 16 + lc) * 32 + ((lg ^ rswz) << 3);
#pragma unroll
  for (int nt = 0; nt < 4; ++nt) {
    const int nl =
        ((nt < 2) ? cg * 32 + nt * 16 : 128 + cg * 32 + (nt - 2) * 16) + lc;
    boff[nt] = nl * 32 + ((lg ^ rswz) << 3);
  }

  f32x4 acc[4][4] = {};
  f32x4 a0, a1;

  // ---- prologue: stage step 0 ----
  a0 = *(const f32x4*)(aG);
  a1 = *(const f32x4*)(aG + 4);
  GLDS16(pbh, &Bh0[ldsB]);
  GLDS16(pbh + 512, &Bh0[ldsB + 512]);
  GLDS16(pbl, &Bl0[ldsB]);
  GLDS16(pbl + 512, &Bl0[ldsB + 512]);
  {
    f16x8 ahw, alw;
#pragma unroll
    for (int e = 0; e < 8; ++e) {
      const float x = (e < 4) ? a0[e] : a1[e - 4];
      const _Float16 h = (_Float16)x;
      ahw[e] = h;
      alw[e] = (_Float16)(x - (float)h);
    }
    *(f16x8*)&Ah[awOff] = ahw;
    *(f16x8*)&Al[awOff] = alw;
  }
  __syncthreads();

#pragma unroll 1
  for (int kt = 0; kt < 16; ++kt) {
    const int knx = (kt + 1) & 15;  // wrap: last iter restages step 0 (unused)
    _Float16* BhN = (kt & 1) ? Bh0 : Bh1;
    _Float16* BlN = (kt & 1) ? Bl0 : Bl1;
    const _Float16* BhC = (kt & 1) ? Bh1 : Bh0;
    const _Float16* BlC = (kt & 1) ? Bl1 : Bl0;

    // issue next-step B (async -> LDS buf^1) and A (-> regs) EARLY
    GLDS16(pbh + knx * 16384, &BhN[ldsB]);
    GLDS16(pbh + knx * 16384 + 512, &BhN[ldsB + 512]);
    GLDS16(pbl + knx * 16384, &BlN[ldsB]);
    GLDS16(pbl + knx * 16384 + 512, &BlN[ldsB + 512]);
    a0 = *(const f32x4*)(aG + knx * 32);
    a1 = *(const f32x4*)(aG + knx * 32 + 4);
    __builtin_amdgcn_sched_barrier(0);  // pin load issue before compute

    // ---- compute step kt ----
    f16x8 ah[4], al[4];
#pragma unroll
    for (int mt = 0; mt < 4; ++mt) {
      ah[mt] = *(const f16x8*)&Ah[aoff[mt]];
      al[mt] = *(const f16x8*)&Al[aoff[mt]];
    }
    __builtin_amdgcn_s_setprio(1);
#pragma unroll
    for (int nt = 0; nt < 4; ++nt) {
      const f16x8 bh = *(const f16x8*)&BhC[boff[nt]];
      const f16x8 bl = *(const f16x8*)&BlC[boff[nt]];
#pragma unroll
      for (int mt = 0; mt < 4; ++mt) {
        acc[mt][nt] = __builtin_amdgcn_mfma_f32_16x16x32_f16(ah[mt], bh,
                                                             acc[mt][nt], 0, 0, 0);
        acc[mt][nt] = __builtin_amdgcn_mfma_f32_16x16x32_f16(ah[mt], bl,
                                                             acc[mt][nt], 0, 0, 0);
        acc[mt][nt] = __builtin_amdgcn_mfma_f32_16x16x32_f16(al[mt], bh,
                                                             acc[mt][nt], 0, 0, 0);
      }
    }
    __builtin_amdgcn_s_setprio(0);

    // convert A(knx) in the MFMA shadow (VALU; depends only on a0/a1)
    f16x8 ahw, alw;
#pragma unroll
    for (int e = 0; e < 8; ++e) {
      const float x = (e < 4) ? a0[e] : a1[e - 4];
      const _Float16 h = (_Float16)x;
      ahw[e] = h;
      alw[e] = (_Float16)(x - (float)h);
    }
    __syncthreads();  // bar1: A-tile reads done; drains B(knx)
    *(f16x8*)&Ah[awOff] = ahw;
    *(f16x8*)&Al[awOff] = alw;
    __syncthreads();  // bar2: A(knx) visible
  }

  // ---- epilogue: gate + reduce over this wave's 32 j-columns ----
  // acc[mt][nt] rr: row = rg*64+mt*16+lg*4+rr, j = c*128+cg*32+nt*16+lc
  // (V at nt 0..1, paired U at nt+2). red aliases Ah: all frag reads done.
#pragma unroll
  for (int mt = 0; mt < 4; ++mt) {
    float rs[4] = {0.f, 0.f, 0.f, 0.f};
#pragma unroll
    for (int nt = 0; nt < 2; ++nt) {
      const int j = c * 128 + cg * 32 + nt * 16 + lc;
      const float bv = bV[j], bu = bU[j], wa = watt[j];
#pragma unroll
      for (int rr = 0; rr < 4; ++rr) {
        const float cV = acc[mt][nt][rr] + bv;
        const float cU = acc[mt][nt + 2][rr] + bu;
        const float e2 = __expf(2.0f * cV);
        const float aV = 1.0f - 2.0f / (e2 + 1.0f);    // tanh
        const float aU = 1.0f / (1.0f + __expf(-cU));  // sigmoid
        rs[rr] += aV * aU * wa;
      }
    }
#pragma unroll
    for (int rr = 0; rr < 4; ++rr) {
      float v = rs[rr];
      v += __shfl_xor(v, 1, 16);
      v += __shfl_xor(v, 2, 16);
      v += __shfl_xor(v, 4, 16);
      v += __shfl_xor(v, 8, 16);
      if (lc == 0) red[(rg * 64 + mt * 16 + lg * 4 + rr) * 5 + cg] = v;
    }
  }
  __syncthreads();
  if (tid < 128)
    rawp[(size_t)c * NROWS + row0 + tid] = red[tid * 5 + 0] + red[tid * 5 + 1] +
                                           red[tid * 5 + 2] + red[tid * 5 + 3];
}

// ---- exclusive scan over 1024 per-thread counts --------------------------
__device__ __forceinline__ int scan1024(int c, int* wred, int tid) {
  const int lane = tid & 63, w = tid >> 6;
  int v = c;
#pragma unroll
  for (int off = 1; off < 64; off <<= 1) {
    const int u = __shfl_up(v, off, 64);
    if (lane >= off) v += u;
  }
  if (lane == 63) wred[w] = v;
  __syncthreads();
  if (tid == 0) {
    int run = 0;
    for (int i = 0; i < 16; ++i) {
      const int a = wred[i];
      wred[i] = run;
      run += a;
    }
  }
  __syncthreads();
  const int res = wred[w] + v - c;
  __syncthreads();
  return res;
}

// ---- K3: fused softmax + top-k threshold + membership + compaction -------
__global__ __launch_bounds__(1024) void select_kernel(
    const float* __restrict__ rawp, const int* __restrict__ psel,
    float* __restrict__ attn_out, int* __restrict__ sel_ws,
    float* __restrict__ out_selidx) {
  const int b = blockIdx.x, t = threadIdx.x;
  const int lane = t & 63, w = t >> 6;
  __shared__ float sraw[N];        // 64 KB
  __shared__ int whist[16][256];   // 16 KB
  __shared__ int ghist[256];
  __shared__ float fred[16];
  __shared__ int wred[16];
  __shared__ float shM, shS;
  __shared__ uint32_t sh_prefix;
  __shared__ int sh_rk;
  const float* r0 = rawp + (size_t)b * N;          // col-half 0 partial
  const float* r1 = rawp + (size_t)NROWS + b * N;  // col-half 1 partial

  // 1. load (sum of two partials; 2-term fp add is order-independent) + max
  float m = -3.0e38f;
  for (int i = 0; i < 16; ++i) {
    const int idx = t + i * 1024;
    const float v = r0[idx] + r1[idx];
    sraw[idx] = v;
    m = fmaxf(m, v);
  }
  for (int off = 32; off > 0; off >>= 1) m = fmaxf(m, __shfl_down(m, off, 64));
  if (lane == 0) fred[w] = m;
  __syncthreads();
  if (t == 0) {
    float mm = fred[0];
    for (int i = 1; i < 16; ++i) mm = fmaxf(mm, fred[i]);
    shM = mm;
  }
  __syncthreads();
  const float M = shM;

  // 2. sum exp (keep the 16 exps in registers for step 3)
  float ex[16];
  float s = 0.f;
  for (int i = 0; i < 16; ++i) {
    ex[i] = expf(sraw[t + i * 1024] - M);
    s += ex[i];
  }
  for (int off = 32; off > 0; off >>= 1) s += __shfl_down(s, off, 64);
  if (lane == 0) fred[w] = s;
  __syncthreads();
  if (t == 0) {
    float ss = 0.f;
    for (int i = 0; i < 16; ++i) ss += fred[i];
    shS = ss;
  }
  __syncthreads();
  const float inv = 1.0f / shS;

  // 3. attn write
  for (int i = 0; i < 16; ++i)
    attn_out[b * N + t + i * 1024] = ex[i] * inv;

  // 4. radix select: threshold key + stable tie count
  uint32_t prefix = 0;
  int rk = N_TOP;
  for (int pass = 3; pass >= 0; --pass) {
    const int sh = pass * 8;
#pragma unroll
    for (int q = 0; q < 4; ++q) whist[w][lane * 4 + q] = 0;
    __syncthreads();
    for (int i = 0; i < 16; ++i) {
      const uint32_t key = f2key(sraw[t + i * 1024]);
      if (pass == 3 || (key >> (sh + 8)) == (prefix >> (sh + 8)))
        atomicAdd(&whist[w][(key >> sh) & 255], 1);
    }
    __syncthreads();
    if (t < 256) {
      int tot = 0;
      for (int ww = 0; ww < 16; ++ww) tot += whist[ww][t];
      ghist[t] = tot;
    }
    __syncthreads();
    int vS = 0, hrev = 0;
    if (t < 256) {
      hrev = ghist[255 - t];
      vS = hrev;
#pragma unroll
      for (int off = 1; off < 64; off <<= 1) {
        const int u2 = __shfl_up(vS, off, 64);
        if (lane >= off) vS += u2;
      }
      if (lane == 63) wred[t >> 6] = vS;
    }
    __syncthreads();
    if (t < 256) {
      int add = 0;
      const int w4 = t >> 6;
      for (int i = 0; i < w4; ++i) add += wred[i];
      const int incl = vS + add, excl = incl - hrev;
      if (incl >= rk && excl < rk) {
        sh_prefix = prefix | ((uint32_t)(255 - t) << sh);
        sh_rk = rk - excl;
      }
    }
    __syncthreads();
    prefix = sh_prefix;
    rk = sh_rk;
    __syncthreads();
  }
  const uint32_t T = prefix;
  const int tieTake = rk;

  // 5. membership + p-rank + psel lookup + selection (contiguous chunks)
  const int n0 = t * 16;
  int cgt = 0, ceq = 0;
  for (int i = 0; i < 16; ++i) {
    const uint32_t key = f2key(sraw[n0 + i]);
    cgt += (key > T);
    ceq += (key == T);
  }
  const int gbase = scan1024(cgt, wred, t);
  const int ebase = scan1024(ceq, wred, t);
  int grun = gbase, erun = ebase;
  unsigned selmask = 0;
  int csel = 0;
  for (int i = 0; i < 16; ++i) {
    const int n = n0 + i;
    const uint32_t key = f2key(sraw[n]);
    const bool gt = key > T, eq = key == T;
    const bool mem = gt || (eq && erun < tieTake);
    int sel;
    if (mem) {
      sel = 1;
    } else {
      const int members_before = grun + (erun < tieTake ? erun : tieTake);
      const int p = n - members_before;
      sel = psel[b * N_REM + p];
    }
    selmask |= (unsigned)sel << i;
    csel += sel;
    grun += gt;
    erun += eq;
  }
  int q = scan1024(csel, wred, t);
  for (int i = 0; i < 16; ++i) {
    if ((selmask >> i) & 1) {
      const int n = n0 + i;
      sel_ws[b * K_SEL + q] = n;
      out_selidx[b * K_SEL + q] = (float)n;
      ++q;
    }
  }
}

// ---- K4: gather selected feature rows ------------------------------------
__global__ __launch_bounds__(128) void gather_kernel(
    const float* __restrict__ feat, const int* __restrict__ sel_ws,
    float* __restrict__ out_sel) {
  const int qa = blockIdx.x;
  const int b = qa / K_SEL;
  const int n = sel_ws[qa];
  const float4* src =
      reinterpret_cast<const float4*>(feat + (size_t)(b * N + n) * D);
  float4* dst = reinterpret_cast<float4*>(out_sel + (size_t)qa * D);
  dst[threadIdx.x] = src[threadIdx.x];
}

extern "C" void kernel_launch(void* const* d_in, const int* in_sizes, int n_in,
                              void* d_out, int out_size, void* d_ws,
                              size_t ws_size, hipStream_t stream) {
  const float* feat = (const float*)d_in[0];
  const float* WV = (const float*)d_in[1];
  const float* bV = (const float*)d_in[2];
  const float* WU = (const float*)d_in[3];
  const float* bU = (const float*)d_in[4];
  const float* watt = (const float*)d_in[5];
  const float* batt = (const float*)d_in[6];
  (void)batt;  // softmax is shift-invariant; b_att cancels in all outputs

  float* out = (float*)d_out;
  float* out_selected = out;                      // B*K_SEL*D floats
  float* out_attn = out + (size_t)B * K_SEL * D;  // B*N floats
  float* out_selidx = out_attn + (size_t)B * N;   // B*K_SEL floats

  _Float16* wt_h = (_Float16*)d_ws;            // 512*512 fp16 = 512 KB
  _Float16* wt_l = wt_h + 512 * 512;           // 512 KB
  float* rawp = (float*)(wt_l + 512 * 512);    // 2*NROWS floats (partials)
  int* psel = (int*)(rawp + 2 * NROWS);        // B*N_REM
  int* sel_ws = psel + B * N_REM;              // B*K_SEL

  prep_kernel<<<68, 256, 0, stream>>>(WV, WU, wt_h, wt_l, psel);
  score_kernel<<<(NROWS / 128) * 2, 512, 0, stream>>>(feat, wt_h, wt_l, bV, bU,
                                                      watt, rawp);
  select_kernel<<<B, 1024, 0, stream>>>(rawp, psel, out_attn, sel_ws,
                                        out_selidx);
  gather_kernel<<<B * K_SEL, 128, 0, stream>>>(feat, sel_ws, out_selected);
}